// Round 2
// baseline (111.297 us; speedup 1.0000x reference)
//
#include <hip/hip_runtime.h>
#include <hip/hip_fp16.h>

#define HH 512
#define WD 512
#define HP 514
#define BN 8
#define CN 3

#define TH 16
#define TW 32

// LDS: sp4 is channel-packed float4; .xyz = ch0..2 and .w DOUBLES AS THE
// img_r (sr) PLANE (written per-dword in phase 2; b128 readers ignore .w, and
// LDS dword writes can't corrupt neighboring dwords -> race-free overlay).
// swm is fp16 (values are fp16-exact copies out of w9 -> bit-identical).
// w9: per-WM-pixel cache of the 9 Gaussian weights from phase 2 (fp16,
// 20 B/px). Total LDS = 13,376 + 1,260 + 12,240 = 26,876 B -> 6 blocks/CU.
#define SP_ROWS (TH + 6)          // 22  img_p rows [h0-2, h0+20)
#define SP_COLS (TW + 6)          // 38
#define SR_ROWS (TH + 4)          // 20  img_r rows [h0-2, h0+18)
#define SR_COLS (TW + 4)          // 36
#define WM_ROWS (TH + 2)          // 18  w_mod rows [h0-1, h0+17)
#define WM_COLS (TW + 2)          // 34
#define WM_PITCH (WM_COLS + 1)    // 35
#define W9_STRIDE 10              // halves per pixel (9 used, 1 pad -> 20 B)

typedef float f2v __attribute__((ext_vector_type(2)));

// Robust per-batch flag read: contract says int32, hedge for bool bytes.
__device__ __forceinline__ int load_flag(const int* __restrict__ p, int b) {
    bool all01 = true;
#pragma unroll
    for (int i = 0; i < BN; ++i) {
        int v = p[i];
        all01 = all01 && (v == 0 || v == 1);
    }
    if (all01) return p[b];
    const unsigned char* pb = (const unsigned char*)p;
    return pb[b] != 0;
}

__device__ __forceinline__ float fast_rcp(float x) {
    return __builtin_amdgcn_rcpf(x);
}

__device__ __forceinline__ float nt_load(const float* p) {
    return __builtin_nontemporal_load(p);
}

// Phase-2 per-pixel body. col is a rotating 3-column register buffer:
// window column j of pixel P lives in slot (j+P)%3 (compile-time indices
// after unrolling -> stays in VGPRs). Math kept in the exact accumulation
// order of the previous version (bit-identical). img_r result is written
// into sp4's .w lane (spw = (float*)sp4, element stride 4).
template <int P>
__device__ __forceinline__ void p2_pixel(const float4 (&col)[3][3], int r, int cc,
                                         bool hok, int w,
                                         float* __restrict__ spw,
                                         __half* __restrict__ w9) {
    float val = 0.f;
    if (hok && (unsigned)w < (unsigned)WD) {
        float sx = 0.f, sy = 0.f, sz = 0.f;
#pragma unroll
        for (int k = 0; k < 9; ++k) {
            const float4 tp = col[(k % 3 + P) % 3][k / 3];
            sx += tp.x; sy += tp.y; sz += tp.z;
        }
        float mx = sx * (1.f / 9.f), my = sy * (1.f / 9.f), mz = sz * (1.f / 9.f);
        float sdx = 0.f, sdy = 0.f, sdz = 0.f;
#pragma unroll
        for (int k = 0; k < 9; ++k) {
            const float4 tp = col[(k % 3 + P) % 3][k / 3];
            float dx = tp.x - mx, dy = tp.y - my, dz = tp.z - mz;
            sdx += dx * dx; sdy += dy * dy; sdz += dz * dz;
        }
        float ivx = 4.f * fast_rcp(sdx);  // 1/(2*var), var = sd/8 (ddof=1)
        float ivy = 4.f * fast_rcp(sdy);
        float ivz = 4.f * fast_rcp(sdz);
        float wk[9];
        float num = 0.f, den = 0.f;
#pragma unroll
        for (int k = 0; k < 9; ++k) {
            const float4 tp = col[(k % 3 + P) % 3][k / 3];
            float dx = tp.x - mx, dy = tp.y - my, dz = tp.z - mz;
            float txx = dx * dx * ivx, tyy = dy * dy * ivy, tzz = dz * dz * ivz;
            float m = fmaxf(txx, fmaxf(tyy, tzz));
            wk[k] = __expf(-m);
            num += (tp.x + tp.y + tp.z) * wk[k];
            den += wk[k];
        }
        val = num * fast_rcp(den);
        // cache the 9 weights (fp16, packed dword writes) for phase 3
        if (r >= 1 && r < SR_ROWS - 1 && cc >= 1 && cc < SR_COLS - 1) {
            int pix = (r - 1) * WM_COLS + (cc - 1);
            unsigned int* wp = (unsigned int*)&w9[pix * W9_STRIDE];
#pragma unroll
            for (int k = 0; k < 4; ++k) {
                __half2 h2 = __floats2half2_rn(wk[2 * k], wk[2 * k + 1]);
                wp[k] = *(unsigned int*)&h2;
            }
            w9[pix * W9_STRIDE + 8] = __float2half_rn(wk[8]);
        }
    }
    spw[(r * SP_COLS + cc) * 4 + 3] = val;   // img_r into the .w lane
}

__global__ __launch_bounds__(256, 6) void fused(const float* __restrict__ img,
                                                const float* __restrict__ noise,
                                                const int* __restrict__ ids_sel,
                                                const int* __restrict__ ids_dil,
                                                int* __restrict__ out) {
    // XCD-aware swizzle (8 XCDs, dispatch round-robins lin%8). Each XCD gets
    // a contiguous 64-tile band (4 tile rows, ~1.7 MB working set < 4 MB L2)
    // from EVERY batch, band index rotated by batch so cheap copy-batches are
    // spread evenly across XCDs (load balance). Bijective: 4096 = 8*8*64.
    int lin = blockIdx.x + 16 * blockIdx.y + 512 * blockIdx.z;
    int xcd = lin & 7;
    int m = lin >> 3;            // 0..511 sequence within this XCD
    int b = m >> 6;              // batch 0..7
    int within = m & 63;         // 0..63 tile within band
    int band = (xcd + b) & 7;    // rotate bands across batches
    int tl = band * 64 + within; // tile id within batch, row-major x-fastest
    int by = tl >> 4, bx = tl & 15;
    int h0 = by * TH, w0 = bx * TW;
    int t = threadIdx.x;

    if (!load_flag(ids_sel, b)) {  // uniform per block: plain uint8 copy, 2 px/thread
        int r = t >> 4, lx = (t & 15) << 1;
#pragma unroll
        for (int c = 0; c < CN; ++c) {
            const float* im = img + (size_t)(b * CN + c) * HH * WD;
            int* op = out + (size_t)(b * CN + c) * HH * WD;
            f2v v = __builtin_nontemporal_load((const f2v*)&im[(h0 + r) * WD + w0 + lx]);
            int2 ov;
            ov.x = ((int)v.x) & 255;
            ov.y = ((int)v.y) & 255;
            __builtin_nontemporal_store(*(const long long*)&ov,
                                        (long long*)&op[(h0 + r) * WD + w0 + lx]);
        }
        return;
    }
    bool dil = load_flag(ids_dil, b) != 0;

    __shared__ float4 sp4[SP_ROWS * SP_COLS];               // 13,376 B
    __shared__ __half swm[WM_ROWS * WM_PITCH];              //  1,260 B
    __shared__ __align__(4) __half w9[WM_ROWS * WM_COLS * W9_STRIDE];  // 12,240 B
    float* spw = (float*)sp4;

    // Phase 1: stage img_p (3ch packed) rows [h0-2,h0+20), cols [w0-2,w0+36).
    // Index-clamped; clamped entries feed only out-of-image pixels (forced 0).
    // Batched: issue ALL global loads (nontemporal: evict-first, keep the
    // poisoned-dirty L3 lines in place) before any LDS write -> max MLP.
    {
        const float* nz = noise + (size_t)b * CN * HP * HP;
        const float* im = img + (size_t)b * CN * HH * WD;
        float a0[4], a1[4], a2[4], b0[4], b1[4], b2[4];
        int sidx[4];
        bool act[4];
#pragma unroll
        for (int q = 0; q < 4; ++q) {
            int idx = t + q * 256;
            act[q] = idx < SP_ROWS * SP_COLS;
            sidx[q] = idx;
            if (act[q]) {
                int r = idx / SP_COLS, cc = idx - r * SP_COLS;
                int ip = h0 - 2 + r, jp = w0 - 2 + cc;
                ip = ip < 0 ? 0 : (ip > HP - 1 ? HP - 1 : ip);
                jp = jp < 0 ? 0 : (jp > HP - 1 ? HP - 1 : jp);
                bool in = (ip >= 1 && ip <= HH && jp >= 1 && jp <= WD);
                int no = ip * HP + jp;
                int io = (ip - 1) * WD + (jp - 1);
                a0[q] = nt_load(nz + no);
                a1[q] = nt_load(nz + HP * HP + no);
                a2[q] = nt_load(nz + 2 * HP * HP + no);
                b0[q] = in ? nt_load(im + io) : 0.f;
                b1[q] = in ? nt_load(im + HH * WD + io) : 0.f;
                b2[q] = in ? nt_load(im + 2 * HH * WD + io) : 0.f;
            }
        }
#pragma unroll
        for (int q = 0; q < 4; ++q) {
            if (act[q]) {
                float4 v;
                v.x = a0[q] + b0[q];
                v.y = a1[q] + b1[q];
                v.z = a2[q] + b2[q];
                v.w = 0.f;
                sp4[sidx[q]] = v;
            }
        }
    }
    __syncthreads();

    // Phase 2: img_r (into sp4.w) + w9 cache for rows [h0-2,h0+18), cols
    // [w0-2,w0+34). 240 active threads, 3 consecutive pixels each, sliding
    // 3-column register buffer: 15 ds_read_b128 per 3 px instead of 27.
    if (t < 240) {
        int r = t / 12;            // 0..19
        int s = t - r * 12;        // 0..11
        int cc0 = 3 * s;           // 0,3,..,33
        int h = h0 - 2 + r;
        bool hok = (h >= 0 && h < HH);
        float4 col[3][3];          // [slot][row]
#pragma unroll
        for (int j = 0; j < 3; ++j)
#pragma unroll
            for (int i = 0; i < 3; ++i)
                col[j][i] = sp4[(r + i) * SP_COLS + cc0 + j];
        p2_pixel<0>(col, r, cc0 + 0, hok, w0 - 2 + cc0 + 0, spw, w9);
#pragma unroll
        for (int i = 0; i < 3; ++i) col[0][i] = sp4[(r + i) * SP_COLS + cc0 + 3];
        p2_pixel<1>(col, r, cc0 + 1, hok, w0 - 2 + cc0 + 1, spw, w9);
#pragma unroll
        for (int i = 0; i < 3; ++i) col[1][i] = sp4[(r + i) * SP_COLS + cc0 + 4];
        p2_pixel<2>(col, r, cc0 + 2, hok, w0 - 2 + cc0 + 2, spw, w9);
    }
    __syncthreads();

    // Phase 3: w_mod for pixel rows [h0-1,h0+17), cols [w0-1,w0+33):
    // argmin/argmax over the img_r window (read from sp4.w), then ONE dynamic
    // LDS u16 read of the cached weight; stored to swm as raw fp16 (bit copy).
    for (int idx = t; idx < WM_ROWS * WM_COLS; idx += 256) {
        int r = idx / WM_COLS, cc = idx - r * WM_COLS;
        int h = h0 - 1 + r, w = w0 - 1 + cc;
        __half wmv = __ushort_as_half((unsigned short)0);
        if (h >= 0 && h < HH && w >= 0 && w < WD) {
            float rv[9];
#pragma unroll
            for (int k = 0; k < 9; ++k)
                rv[k] = spw[((r + k / 3) * SP_COLS + cc + k % 3) * 4 + 3];
            int amin = 0, amax = 0;
            float vmin = rv[0], vmax = rv[0];
#pragma unroll
            for (int k = 1; k < 9; ++k) {
                if (rv[k] < vmin) { vmin = rv[k]; amin = k; }  // first occurrence
                if (rv[k] > vmax) { vmax = rv[k]; amax = k; }
            }
            int ksel = dil ? amax : amin;
            wmv = w9[idx * W9_STRIDE + ksel];
        }
        swm[r * WM_PITCH + cc] = wmv;
    }
    __syncthreads();

    // Phase 4: final weighted average, 2 adjacent px per thread (rotating
    // column buffer, 12 b128 taps instead of 18), 3 channels at once, packed
    // dwordx2 nontemporal stores. swm halves are fp16-exact -> identical math.
    {
        int ly = t >> 4;            // 0..15
        int lx = (t & 15) << 1;     // 0,2,..,30
        float4 c4[3][3];            // [slot][row]
#pragma unroll
        for (int j = 0; j < 3; ++j)
#pragma unroll
            for (int i = 0; i < 3; ++i)
                c4[j][i] = sp4[(ly + 2 + i) * SP_COLS + lx + 2 + j];
        float ws[4][3];
#pragma unroll
        for (int j = 0; j < 4; ++j)
#pragma unroll
            for (int i = 0; i < 3; ++i)
                ws[j][i] = __half2float(swm[(ly + i) * WM_PITCH + lx + j]);
        int2 o0, o1, o2;
        {   // px q=0 at (ly, lx): window col j -> slot j
            float den = 0.f, nx = 0.f, ny = 0.f, nz2 = 0.f;
#pragma unroll
            for (int k = 0; k < 9; ++k) {
                const float wkk = ws[k % 3][k / 3];
                const float4 tp = c4[k % 3][k / 3];
                den += wkk;
                nx += tp.x * wkk; ny += tp.y * wkk; nz2 += tp.z * wkk;
            }
            float rden = 1.f / den;
            o0.x = ((int)(nx * rden)) & 255;
            o1.x = ((int)(ny * rden)) & 255;
            o2.x = ((int)(nz2 * rden)) & 255;
        }
#pragma unroll
        for (int i = 0; i < 3; ++i) c4[0][i] = sp4[(ly + 2 + i) * SP_COLS + lx + 5];
        {   // px q=1 at (ly, lx+1): window col j -> slot (j+1)%3
            float den = 0.f, nx = 0.f, ny = 0.f, nz2 = 0.f;
#pragma unroll
            for (int k = 0; k < 9; ++k) {
                const float wkk = ws[k % 3 + 1][k / 3];
                const float4 tp = c4[(k % 3 + 1) % 3][k / 3];
                den += wkk;
                nx += tp.x * wkk; ny += tp.y * wkk; nz2 += tp.z * wkk;
            }
            float rden = 1.f / den;
            o0.y = ((int)(nx * rden)) & 255;
            o1.y = ((int)(ny * rden)) & 255;
            o2.y = ((int)(nz2 * rden)) & 255;
        }
        size_t o = ((size_t)b * CN * HH + h0 + ly) * WD + w0 + lx;
        __builtin_nontemporal_store(*(const long long*)&o0, (long long*)&out[o]);
        __builtin_nontemporal_store(*(const long long*)&o1,
                                    (long long*)&out[o + (size_t)HH * WD]);
        __builtin_nontemporal_store(*(const long long*)&o2,
                                    (long long*)&out[o + 2 * (size_t)HH * WD]);
    }
}

extern "C" void kernel_launch(void* const* d_in, const int* in_sizes, int n_in,
                              void* d_out, int out_size, void* d_ws, size_t ws_size,
                              hipStream_t stream) {
    const float* img   = (const float*)d_in[0];
    const float* noise = (const float*)d_in[1];
    const int* ids_sel = (const int*)d_in[2];
    const int* ids_dil = (const int*)d_in[3];
    int* out = (int*)d_out;

    dim3 grid(WD / TW, HH / TH, BN);  // 16 x 32 x 8 = 4096 blocks
    fused<<<grid, 256, 0, stream>>>(img, noise, ids_sel, ids_dil, out);
}

// Round 3
// 110.561 us; speedup vs baseline: 1.0067x; 1.0067x over previous
//
#include <hip/hip_runtime.h>
#include <hip/hip_fp16.h>

#define HH 512
#define WD 512
#define HP 514
#define BN 8
#define CN 3

#define TH 16
#define TW 32

// LDS tiles. sp4 is channel-packed float4 (.xyz = ch0..2) so one tap = one
// 16B-aligned ds_read_b128. sr/swm scalar with odd pitch (conflict-free).
// w9: per-WM-pixel cache of the 9 Gaussian weights computed in phase 2
// (fp16, 20B/px, 5-dword stride -> full bank spread), so phase 3 never
// recomputes window stats. Total 31,096 B -> LDS-fits 4 blocks/CU easily
// (the binding limit is VGPR via __launch_bounds__(256,4)).
#define SP_ROWS (TH + 6)          // 22  img_p rows [h0-2, h0+20)
#define SP_COLS (TW + 6)          // 38
#define SP_N (SP_ROWS * SP_COLS)  // 836
#define SR_ROWS (TH + 4)          // 20  img_r rows [h0-2, h0+18)
#define SR_COLS (TW + 4)          // 36
#define SR_PITCH (SR_COLS + 1)    // 37
#define WM_ROWS (TH + 2)          // 18  w_mod rows [h0-1, h0+17)
#define WM_COLS (TW + 2)          // 34
#define WM_PITCH (WM_COLS + 1)    // 35
#define W9_STRIDE 10              // halves per pixel (9 used, 1 pad -> 20 B)

typedef float f2v __attribute__((ext_vector_type(2)));

// Robust per-batch flag read: contract says int32, hedge for bool bytes.
__device__ __forceinline__ int load_flag(const int* __restrict__ p, int b) {
    bool all01 = true;
#pragma unroll
    for (int i = 0; i < BN; ++i) {
        int v = p[i];
        all01 = all01 && (v == 0 || v == 1);
    }
    if (all01) return p[b];
    const unsigned char* pb = (const unsigned char*)p;
    return pb[b] != 0;
}

__device__ __forceinline__ float fast_rcp(float x) {
    return __builtin_amdgcn_rcpf(x);
}

// Phase-1 prefetch registers: RAW loaded values (no adds here!) so the
// compiler sinks the s_waitcnt vmcnt to p1_write's first use -> the loads
// stay in flight across phases 3+4 of the previous tile.
struct P1R {
    float a0[4], a1[4], a2[4];   // noise ch0..2
    float b0[4], b1[4], b2[4];   // img   ch0..2 (0 when out of image)
};

__device__ __forceinline__ void p1_issue(const float* __restrict__ nz,
                                         const float* __restrict__ im,
                                         int h0, int w0, int t, P1R& R) {
#pragma unroll
    for (int q = 0; q < 4; ++q) {
        int idx = t + q * 256;
        if (idx < SP_N) {
            int r = idx / SP_COLS, cc = idx - r * SP_COLS;
            int ip = h0 - 2 + r, jp = w0 - 2 + cc;
            ip = ip < 0 ? 0 : (ip > HP - 1 ? HP - 1 : ip);
            jp = jp < 0 ? 0 : (jp > HP - 1 ? HP - 1 : jp);
            bool in = (ip >= 1 && ip <= HH && jp >= 1 && jp <= WD);
            int no = ip * HP + jp;
            int io = (ip - 1) * WD + (jp - 1);
            R.a0[q] = nz[no];
            R.a1[q] = nz[HP * HP + no];
            R.a2[q] = nz[2 * HP * HP + no];
            R.b0[q] = in ? im[io] : 0.f;
            R.b1[q] = in ? im[HH * WD + io] : 0.f;
            R.b2[q] = in ? im[2 * HH * WD + io] : 0.f;
        }
    }
}

__device__ __forceinline__ void p1_write(float4* __restrict__ sp4, int t,
                                         const P1R& R) {
#pragma unroll
    for (int q = 0; q < 4; ++q) {
        int idx = t + q * 256;
        if (idx < SP_N) {
            float4 v;
            v.x = R.a0[q] + R.b0[q];
            v.y = R.a1[q] + R.b1[q];
            v.z = R.a2[q] + R.b2[q];
            v.w = 0.f;
            sp4[idx] = v;
        }
    }
}

// Phase-2 per-pixel body. col is a rotating 3-column register buffer:
// window column j of pixel P lives in slot (j+P)%3 (compile-time indices
// after unrolling -> stays in VGPRs). Math kept in the exact accumulation
// order of the previous versions (bit-identical).
template <int P>
__device__ __forceinline__ void p2_pixel(const float4 (&col)[3][3], int r, int cc,
                                         bool hok, int w,
                                         float* __restrict__ sr,
                                         __half* __restrict__ w9) {
    float val = 0.f;
    if (hok && (unsigned)w < (unsigned)WD) {
        float sx = 0.f, sy = 0.f, sz = 0.f;
#pragma unroll
        for (int k = 0; k < 9; ++k) {
            const float4 tp = col[(k % 3 + P) % 3][k / 3];
            sx += tp.x; sy += tp.y; sz += tp.z;
        }
        float mx = sx * (1.f / 9.f), my = sy * (1.f / 9.f), mz = sz * (1.f / 9.f);
        float sdx = 0.f, sdy = 0.f, sdz = 0.f;
#pragma unroll
        for (int k = 0; k < 9; ++k) {
            const float4 tp = col[(k % 3 + P) % 3][k / 3];
            float dx = tp.x - mx, dy = tp.y - my, dz = tp.z - mz;
            sdx += dx * dx; sdy += dy * dy; sdz += dz * dz;
        }
        float ivx = 4.f * fast_rcp(sdx);  // 1/(2*var), var = sd/8 (ddof=1)
        float ivy = 4.f * fast_rcp(sdy);
        float ivz = 4.f * fast_rcp(sdz);
        float wk[9];
        float num = 0.f, den = 0.f;
#pragma unroll
        for (int k = 0; k < 9; ++k) {
            const float4 tp = col[(k % 3 + P) % 3][k / 3];
            float dx = tp.x - mx, dy = tp.y - my, dz = tp.z - mz;
            float txx = dx * dx * ivx, tyy = dy * dy * ivy, tzz = dz * dz * ivz;
            float m = fmaxf(txx, fmaxf(tyy, tzz));
            wk[k] = __expf(-m);
            num += (tp.x + tp.y + tp.z) * wk[k];
            den += wk[k];
        }
        val = num * fast_rcp(den);
        // cache the 9 weights (fp16, packed dword writes) for phase 3
        if (r >= 1 && r < SR_ROWS - 1 && cc >= 1 && cc < SR_COLS - 1) {
            int pix = (r - 1) * WM_COLS + (cc - 1);
            unsigned int* wp = (unsigned int*)&w9[pix * W9_STRIDE];
#pragma unroll
            for (int k = 0; k < 4; ++k) {
                __half2 h2 = __floats2half2_rn(wk[2 * k], wk[2 * k + 1]);
                wp[k] = *(unsigned int*)&h2;
            }
            w9[pix * W9_STRIDE + 8] = __float2half_rn(wk[8]);
        }
    }
    sr[r * SR_PITCH + cc] = val;
}

__device__ __forceinline__ void p2_phase(const float4* __restrict__ sp4,
                                         float* __restrict__ sr,
                                         __half* __restrict__ w9,
                                         int h0, int w0, int t) {
    // 240 active threads, 3 consecutive pixels each, sliding 3-column
    // register buffer: 15 ds_read_b128 per 3 px instead of 27.
    if (t < 240) {
        int r = t / 12;            // 0..19
        int s = t - r * 12;        // 0..11
        int cc0 = 3 * s;           // 0,3,..,33
        int h = h0 - 2 + r;
        bool hok = (h >= 0 && h < HH);
        float4 col[3][3];          // [slot][row]
#pragma unroll
        for (int j = 0; j < 3; ++j)
#pragma unroll
            for (int i = 0; i < 3; ++i)
                col[j][i] = sp4[(r + i) * SP_COLS + cc0 + j];
        p2_pixel<0>(col, r, cc0 + 0, hok, w0 - 2 + cc0 + 0, sr, w9);
#pragma unroll
        for (int i = 0; i < 3; ++i) col[0][i] = sp4[(r + i) * SP_COLS + cc0 + 3];
        p2_pixel<1>(col, r, cc0 + 1, hok, w0 - 2 + cc0 + 1, sr, w9);
#pragma unroll
        for (int i = 0; i < 3; ++i) col[1][i] = sp4[(r + i) * SP_COLS + cc0 + 4];
        p2_pixel<2>(col, r, cc0 + 2, hok, w0 - 2 + cc0 + 2, sr, w9);
    }
}

__device__ __forceinline__ void p3_phase(const float* __restrict__ sr,
                                         const __half* __restrict__ w9,
                                         float* __restrict__ swm,
                                         int h0, int w0, int t, bool dil) {
    for (int idx = t; idx < WM_ROWS * WM_COLS; idx += 256) {
        int r = idx / WM_COLS, cc = idx - r * WM_COLS;
        int h = h0 - 1 + r, w = w0 - 1 + cc;
        float wmv = 0.f;
        if (h >= 0 && h < HH && w >= 0 && w < WD) {
            float rv[9];
#pragma unroll
            for (int k = 0; k < 9; ++k)
                rv[k] = sr[(r + k / 3) * SR_PITCH + cc + k % 3];
            int amin = 0, amax = 0;
            float vmin = rv[0], vmax = rv[0];
#pragma unroll
            for (int k = 1; k < 9; ++k) {
                if (rv[k] < vmin) { vmin = rv[k]; amin = k; }  // first occurrence
                if (rv[k] > vmax) { vmax = rv[k]; amax = k; }
            }
            int ksel = dil ? amax : amin;
            wmv = __half2float(w9[idx * W9_STRIDE + ksel]);
        }
        swm[r * WM_PITCH + cc] = wmv;
    }
}

__device__ __forceinline__ void p4_phase(const float4* __restrict__ sp4,
                                         const float* __restrict__ swm,
                                         int* __restrict__ out,
                                         int b, int h0, int w0, int t) {
    // 2 adjacent px per thread (rotating column buffer, 12 b128 taps instead
    // of 18), 3 channels at once, packed dwordx2 nontemporal stores.
    int ly = t >> 4;            // 0..15
    int lx = (t & 15) << 1;     // 0,2,..,30
    float4 c4[3][3];            // [slot][row]
#pragma unroll
    for (int j = 0; j < 3; ++j)
#pragma unroll
        for (int i = 0; i < 3; ++i)
            c4[j][i] = sp4[(ly + 2 + i) * SP_COLS + lx + 2 + j];
    float ws[4][3];
#pragma unroll
    for (int j = 0; j < 4; ++j)
#pragma unroll
        for (int i = 0; i < 3; ++i)
            ws[j][i] = swm[(ly + i) * WM_PITCH + lx + j];
    int2 o0, o1, o2;
    {   // px q=0 at (ly, lx): window col j -> slot j
        float den = 0.f, nx = 0.f, ny = 0.f, nz2 = 0.f;
#pragma unroll
        for (int k = 0; k < 9; ++k) {
            const float wkk = ws[k % 3][k / 3];
            const float4 tp = c4[k % 3][k / 3];
            den += wkk;
            nx += tp.x * wkk; ny += tp.y * wkk; nz2 += tp.z * wkk;
        }
        float rden = 1.f / den;
        o0.x = ((int)(nx * rden)) & 255;
        o1.x = ((int)(ny * rden)) & 255;
        o2.x = ((int)(nz2 * rden)) & 255;
    }
#pragma unroll
    for (int i = 0; i < 3; ++i) c4[0][i] = sp4[(ly + 2 + i) * SP_COLS + lx + 5];
    {   // px q=1 at (ly, lx+1): window col j -> slot (j+1)%3
        float den = 0.f, nx = 0.f, ny = 0.f, nz2 = 0.f;
#pragma unroll
        for (int k = 0; k < 9; ++k) {
            const float wkk = ws[k % 3 + 1][k / 3];
            const float4 tp = c4[(k % 3 + 1) % 3][k / 3];
            den += wkk;
            nx += tp.x * wkk; ny += tp.y * wkk; nz2 += tp.z * wkk;
        }
        float rden = 1.f / den;
        o0.y = ((int)(nx * rden)) & 255;
        o1.y = ((int)(ny * rden)) & 255;
        o2.y = ((int)(nz2 * rden)) & 255;
    }
    size_t o = ((size_t)b * CN * HH + h0 + ly) * WD + w0 + lx;
    __builtin_nontemporal_store(*(const long long*)&o0, (long long*)&out[o]);
    __builtin_nontemporal_store(*(const long long*)&o1,
                                (long long*)&out[o + (size_t)HH * WD]);
    __builtin_nontemporal_store(*(const long long*)&o2,
                                (long long*)&out[o + 2 * (size_t)HH * WD]);
}

__global__ __launch_bounds__(256, 4) void fused(const float* __restrict__ img,
                                                const float* __restrict__ noise,
                                                const int* __restrict__ ids_sel,
                                                const int* __restrict__ ids_dil,
                                                int* __restrict__ out) {
    // Each block handles TWO vertically-adjacent 16x32 tiles (software
    // pipeline: tile-B global loads issued during tile-A phases 3+4).
    // XCD-aware swizzle (8 XCDs, dispatch round-robins lin%8). Each XCD gets
    // a contiguous 32-pair band (4 tile rows, ~1.7 MB < 4 MB L2) from EVERY
    // batch, band rotated by batch for load balance. Bijective: 2048 = 8*8*32.
    int lin = blockIdx.x + 16 * blockIdx.y + 256 * blockIdx.z;
    int xcd = lin & 7;
    int m = lin >> 3;            // 0..255 sequence within this XCD
    int b = m >> 5;              // batch 0..7
    int within = m & 31;         // 0..31 pair within band
    int band = (xcd + b) & 7;    // rotate bands across batches
    int tl = band * 32 + within; // pair id within batch, row-major x-fastest
    int byp = tl >> 4, bx = tl & 15;
    int h0A = (2 * byp) * TH, w0 = bx * TW;
    int h0B = h0A + TH;
    int t = threadIdx.x;

    if (!load_flag(ids_sel, b)) {  // uniform per block: plain uint8 copy, 2 px/thread/tile
        int r = t >> 4, lx = (t & 15) << 1;
#pragma unroll
        for (int tt = 0; tt < 2; ++tt) {
            int h0 = tt ? h0B : h0A;
#pragma unroll
            for (int c = 0; c < CN; ++c) {
                const float* im = img + (size_t)(b * CN + c) * HH * WD;
                int* op = out + (size_t)(b * CN + c) * HH * WD;
                f2v v = *(const f2v*)&im[(h0 + r) * WD + w0 + lx];
                int2 ov;
                ov.x = ((int)v.x) & 255;
                ov.y = ((int)v.y) & 255;
                __builtin_nontemporal_store(*(const long long*)&ov,
                                            (long long*)&op[(h0 + r) * WD + w0 + lx]);
            }
        }
        return;
    }
    bool dil = load_flag(ids_dil, b) != 0;

    __shared__ float4 sp4[SP_N];                             // 13,376 B
    __shared__ float sr[SR_ROWS * SR_PITCH];                 //  2,960 B
    __shared__ float swm[WM_ROWS * WM_PITCH];                //  2,520 B
    __shared__ __align__(4) __half w9[WM_ROWS * WM_COLS * W9_STRIDE];  // 12,240 B

    const float* nz = noise + (size_t)b * CN * HP * HP;
    const float* im = img + (size_t)b * CN * HH * WD;

    // ---- tile A ----
    {
        P1R RA;
        p1_issue(nz, im, h0A, w0, t, RA);
        p1_write(sp4, t, RA);
    }
    __syncthreads();
    p2_phase(sp4, sr, w9, h0A, w0, t);
    __syncthreads();
    // Prefetch tile B now: raw loads held in regs, vmcnt-wait sinks to
    // p1_write(RB) AFTER phases 3+4(A) -> HBM streams under compute.
    P1R RB;
    p1_issue(nz, im, h0B, w0, t, RB);
    p3_phase(sr, w9, swm, h0A, w0, t, dil);
    __syncthreads();
    p4_phase(sp4, swm, out, b, h0A, w0, t);
    __syncthreads();               // all reads of sp4(A) done
    // ---- tile B ----
    p1_write(sp4, t, RB);
    __syncthreads();
    p2_phase(sp4, sr, w9, h0B, w0, t);
    __syncthreads();
    p3_phase(sr, w9, swm, h0B, w0, t, dil);
    __syncthreads();
    p4_phase(sp4, swm, out, b, h0B, w0, t);
}

extern "C" void kernel_launch(void* const* d_in, const int* in_sizes, int n_in,
                              void* d_out, int out_size, void* d_ws, size_t ws_size,
                              hipStream_t stream) {
    const float* img   = (const float*)d_in[0];
    const float* noise = (const float*)d_in[1];
    const int* ids_sel = (const int*)d_in[2];
    const int* ids_dil = (const int*)d_in[3];
    int* out = (int*)d_out;

    dim3 grid(WD / TW, HH / (2 * TH), BN);  // 16 x 16 x 8 = 2048 blocks
    fused<<<grid, 256, 0, stream>>>(img, noise, ids_sel, ids_dil, out);
}